// Round 2
// baseline (81.929 us; speedup 1.0000x reference)
//
#include <hip/hip_runtime.h>

// LSHAttention: reference returns ONLY sticker = argsort(buckets) [B,S] int32.
// B=4, S=4096, D=1024, NR=32, 64 buckets.
// k1: split-K GEMM (Q global->reg, R^T in LDS, 1 B LDS/FMA) -> partials P
// k1c: combine K-halves + argmax -> buckets + chunk hist
// k2: offset scan; k3: stable scatter. (k2/k3 verified in round 1, absmax 0.)

#define B_DIM 4
#define S_LEN 4096
#define D_DIM 1024
#define NR 32
#define NBK 64
#define TM 64                    // tokens per chunk / block
#define NCHUNK (S_LEN / TM)      // 64
#define KSEG 128                 // k per wave
#define KHALF 512                // k per block
#define RST_STRIDE (KHALF + 4)   // 516 floats: 16B-aligned rows, bank-spread

// grid = B*NCHUNK*2 = 512 blocks (2/CU, 8 waves/CU), 256 threads.
__global__ __launch_bounds__(256) void k1_gemm(
    const float* __restrict__ Q, const float* __restrict__ R,
    float* __restrict__ P)
{
    __shared__ __align__(16) float Rst[NR][RST_STRIDE];   // ~66 KB, reused as sbuf

    const int bid = blockIdx.x;
    const int khalf = bid & 1;
    const int bc = bid >> 1;        // b*64 + chunk
    const int b = bc >> 6;
    const int chunk = bc & 63;
    const int t = threadIdx.x;

    // ---- stage R^T for this K-half: 512 k x 32 r (coalesced float4 reads) ----
    const float* Rb = R + (size_t)b * D_DIM * NR + (size_t)khalf * KHALF * NR;
#pragma unroll
    for (int i = 0; i < 16; ++i) {
        int f = t + 256 * i;              // float4 id in [0,4096)
        int k = f >> 3;                   // [0,512)
        int rq = (f & 7) * 4;             // r quad
        float4 v = *reinterpret_cast<const float4*>(Rb + (size_t)k * NR + rq);
        Rst[rq + 0][k] = v.x;
        Rst[rq + 1][k] = v.y;
        Rst[rq + 2][k] = v.z;
        Rst[rq + 3][k] = v.w;
    }
    __syncthreads();

    const int w = t >> 6;           // wave -> k-segment within half
    const int lane = t & 63;
    const int tg = lane >> 2;       // 16 token groups x 4 tokens
    const int l = lane & 3;         // 4-lane k split

    const float* Qb = Q + ((size_t)b * S_LEN + chunk * TM + tg * 4) * D_DIM
                    + khalf * KHALF + w * KSEG + l * 4;

    float acc[4][NR];
#pragma unroll
    for (int j = 0; j < 4; ++j)
#pragma unroll
        for (int r = 0; r < NR; ++r) acc[j][r] = 0.f;

    float4 qreg[4], qnext[4];
#pragma unroll
    for (int j = 0; j < 4; ++j)
        qreg[j] = *reinterpret_cast<const float4*>(Qb + (size_t)j * D_DIM);

    const int koff0 = w * KSEG + l * 4;

    for (int s = 0; s < KSEG / 16; ++s) {   // 8 steps x 16 k
        if (s + 1 < KSEG / 16) {
#pragma unroll
            for (int j = 0; j < 4; ++j)
                qnext[j] = *reinterpret_cast<const float4*>(
                    Qb + (size_t)j * D_DIM + (s + 1) * 16);
        }
        const int koff = koff0 + s * 16;
#pragma unroll
        for (int r = 0; r < NR; ++r) {
            float4 rv = *reinterpret_cast<const float4*>(&Rst[r][koff]);
#pragma unroll
            for (int j = 0; j < 4; ++j) {
                acc[j][r] = fmaf(qreg[j].x, rv.x, acc[j][r]);
                acc[j][r] = fmaf(qreg[j].y, rv.y, acc[j][r]);
                acc[j][r] = fmaf(qreg[j].z, rv.z, acc[j][r]);
                acc[j][r] = fmaf(qreg[j].w, rv.w, acc[j][r]);
            }
        }
        if (s + 1 < KSEG / 16) {
#pragma unroll
            for (int j = 0; j < 4; ++j) qreg[j] = qnext[j];
        }
    }

    // ---- butterfly all-reduce over the 4 k-lanes (aligned group of 4) ----
#pragma unroll
    for (int j = 0; j < 4; ++j)
#pragma unroll
        for (int r = 0; r < NR; ++r) {
            acc[j][r] += __shfl_xor(acc[j][r], 1, 64);
            acc[j][r] += __shfl_xor(acc[j][r], 2, 64);
        }

    // ---- combine the block's 4 waves in LDS (reuse Rst), write P ----
    __syncthreads();                        // all Rst reads done
    float* sbuf = &Rst[0][0];               // [w][tok][r] stride 33 (bank-spread)
#pragma unroll
    for (int j = 0; j < 4; ++j) {
        int tokj = tg * 4 + j;
#pragma unroll
        for (int h = 0; h < 8; ++h) {
            int r = l * 8 + h;              // lane l owns r-slice l*8..+7
            sbuf[(w * 64 + tokj) * 33 + r] = acc[j][r];
        }
    }
    __syncthreads();

    const int tok = t & 63;
    const int rq2 = t >> 6;
    float* Pout = P + (((size_t)bc * 2 + khalf) * NR) * TM;
#pragma unroll
    for (int h = 0; h < 8; ++h) {
        int r = rq2 * 8 + h;
        float v = sbuf[(0 * 64 + tok) * 33 + r] + sbuf[(1 * 64 + tok) * 33 + r]
                + sbuf[(2 * 64 + tok) * 33 + r] + sbuf[(3 * 64 + tok) * 33 + r];
        Pout[(size_t)r * TM + tok] = v;     // P[bc][khalf][r][tok], coalesced
    }
}

// grid = 256 blocks (b,chunk), 256 thr: sum 2 K-halves, argmax, bucket, hist.
__global__ __launch_bounds__(256) void k1c_combine(
    const float* __restrict__ P,
    int* __restrict__ buckets, int* __restrict__ hist)
{
    __shared__ float xs[TM][NR + 1];
    __shared__ int cnt[NBK];

    const int bc = blockIdx.x;     // b*64 + chunk
    const int b = bc >> 6;
    const int chunk = bc & 63;
    const int t = threadIdx.x;
    const int tok = t & 63;
    const int rq = t >> 6;

    const float* Pb = P + (size_t)bc * 2 * NR * TM;
#pragma unroll
    for (int h = 0; h < 8; ++h) {
        int r = rq * 8 + h;
        float s = Pb[((size_t)0 * NR + r) * TM + tok]
                + Pb[((size_t)1 * NR + r) * TM + tok];
        xs[tok][r] = s;
    }
    if (t < NBK) cnt[t] = 0;
    __syncthreads();

    if (t < TM) {
        // argmax(concat[xR,-xR]) with first-occurrence tie-break:
        float m1 = xs[t][0]; int i1 = 0;
        float m2 = m1;       int i2 = 0;
#pragma unroll
        for (int r = 1; r < NR; ++r) {
            float v = xs[t][r];
            if (v > m1) { m1 = v; i1 = r; }
            if (v < m2) { m2 = v; i2 = r; }
        }
        int bk = (m1 >= -m2) ? i1 : (NR + i2);
        buckets[(size_t)b * S_LEN + chunk * TM + t] = bk;
        atomicAdd(&cnt[bk], 1);
    }
    __syncthreads();
    if (t < NBK) hist[(size_t)bc * NBK + t] = cnt[t];
}

// One block, 256 threads: thread = (batch b = t/64, bucket bk = t%64).
__global__ __launch_bounds__(256) void k2_scan(
    const int* __restrict__ hist, int* __restrict__ chunkOffset)
{
    const int t = threadIdx.x;
    const int b = t >> 6;
    const int bk = t & 63;
    const int lane = t & 63;

    int total = 0;
    for (int c = 0; c < NCHUNK; ++c)
        total += hist[((size_t)b * NCHUNK + c) * NBK + bk];

    int incl = total;
#pragma unroll
    for (int off = 1; off < 64; off <<= 1) {
        int n = __shfl_up(incl, off, 64);
        if (lane >= off) incl += n;
    }
    int run = incl - total;   // exclusive prefix over buckets = bucketStart

    for (int c = 0; c < NCHUNK; ++c) {
        int h = hist[((size_t)b * NCHUNK + c) * NBK + bk];
        chunkOffset[((size_t)b * NCHUNK + c) * NBK + bk] = run;
        run += h;
    }
}

// Stable scatter: wave = 64 consecutive tokens (one chunk).
__global__ __launch_bounds__(256) void k3_scatter(
    const int* __restrict__ buckets, const int* __restrict__ chunkOffset,
    int* __restrict__ out)
{
    const int gid = blockIdx.x * 256 + threadIdx.x;  // 0..16383
    const int b = gid >> 12;
    const int s = gid & (S_LEN - 1);
    const int chunk = s >> 6;
    const int lane = threadIdx.x & 63;

    const int bk = buckets[gid];

    unsigned long long m = ~0ull;
#pragma unroll
    for (int i = 0; i < 6; ++i) {
        unsigned long long bi = __ballot((bk >> i) & 1);
        m &= ((bk >> i) & 1) ? bi : ~bi;
    }
    int rank = __popcll(m & ((1ull << lane) - 1ull));

    int pos = chunkOffset[((size_t)b * NCHUNK + chunk) * NBK + bk] + rank;
    out[(size_t)b * S_LEN + pos] = s;
}

extern "C" void kernel_launch(void* const* d_in, const int* in_sizes, int n_in,
                              void* d_out, int out_size, void* d_ws, size_t ws_size,
                              hipStream_t stream) {
    const float* Q = (const float*)d_in[0];
    // d_in[1] = key, d_in[2] = value: dead code in the reference, never read.
    const float* R = (const float*)d_in[3];

    float* P          = (float*)d_ws;                          // 4 MB partials
    int*   buckets    = (int*)(P + (size_t)B_DIM * NCHUNK * 2 * NR * TM);
    int*   hist       = buckets + B_DIM * S_LEN;
    int*   chunkOffset= hist + B_DIM * NCHUNK * NBK;

    k1_gemm   <<<B_DIM * NCHUNK * 2, 256, 0, stream>>>(Q, R, P);
    k1c_combine<<<B_DIM * NCHUNK,     256, 0, stream>>>(P, buckets, hist);
    k2_scan   <<<1,                   256, 0, stream>>>(hist, chunkOffset);
    k3_scatter<<<(B_DIM * S_LEN)/256, 256, 0, stream>>>(buckets, chunkOffset, (int*)d_out);
}